// Round 1
// baseline (1189.784 us; speedup 1.0000x reference)
//
#include <hip/hip_runtime.h>
#include <math.h>

// Problem constants
// hidden [2][512][2048], memory [8192][1024], Wq [2048][256], Wk/Wv [1024][256],
// Wo [256][2048], log_beta[4], g_s/b_s[2048], g_m/b_m[1024]
// out: output [2][512][2048] then converged [2][512][256], f32.

__device__ __forceinline__ float wred_add(float v) {
#pragma unroll
  for (int off = 32; off >= 1; off >>= 1) v += __shfl_xor(v, off, 64);
  return v;
}
__device__ __forceinline__ float wred_max(float v) {
#pragma unroll
  for (int off = 32; off >= 1; off >>= 1) v = fmaxf(v, __shfl_xor(v, off, 64));
  return v;
}

// ---------------- LayerNorm row stats: mu, 1/sqrt(var+eps) ----------------
__global__ __launch_bounds__(256) void ln_stats_kernel(
    const float* __restrict__ X, int cols, float* __restrict__ mu,
    float* __restrict__ rs) {
  int row = blockIdx.x, tid = threadIdx.x;
  const float4* xr = (const float4*)(X + (size_t)row * cols);
  int nv = cols >> 10;  // cols / (4*256); cols is 2048 or 1024
  float s = 0.f, s2 = 0.f;
  for (int v = 0; v < nv; ++v) {
    float4 x4 = xr[tid + (v << 8)];
    s += x4.x + x4.y + x4.z + x4.w;
    s2 += x4.x * x4.x + x4.y * x4.y + x4.z * x4.z + x4.w * x4.w;
  }
  s = wred_add(s);
  s2 = wred_add(s2);
  __shared__ float rb[8];
  int wid = tid >> 6, lane = tid & 63;
  if (lane == 0) { rb[wid] = s; rb[4 + wid] = s2; }
  __syncthreads();
  if (tid == 0) {
    float S = rb[0] + rb[1] + rb[2] + rb[3];
    float S2 = rb[4] + rb[5] + rb[6] + rb[7];
    float m = S / (float)cols;
    float var = S2 / (float)cols - m * m;
    mu[row] = m;
    rs[row] = 1.f / sqrtf(var + 1e-5f);
  }
}

// ---------------- Generic f32 tiled GEMM: C = LN(A) @ W ----------------
// BM=BN=64, BK=16, 256 threads, 4x4 micro-tile.
// a_mode: 0 = A row-major [M][Kd] with LN(mu,rs,gam,bet) fused
//         1 = A is xi-layout [B][H][S][D] (row m=(b*512+s), col k=(h*64+d)), no LN
// out_mode: 0 = xi-layout [B][H][S][D] (row m=(b,s), col n=(h,d))
//           1 = K^T layout: out[n*8192 + m]
//           2 = V layout:   out[((n>>6)*8192 + m)*64 + (n&63)]
//           3 = plain row-major out[m*N + n]
__global__ __launch_bounds__(256) void gemm_ln_kernel(
    const float* __restrict__ A, const float* __restrict__ W,
    const float* __restrict__ mu, const float* __restrict__ rs,
    const float* __restrict__ gam, const float* __restrict__ bet,
    float* __restrict__ out, int M, int Kd, int N, int a_mode, int out_mode) {
  __shared__ __align__(16) float As[16][64];  // [k][m]
  __shared__ __align__(16) float Bs[16][64];  // [k][n]
  int tid = threadIdx.x;
  int bm = blockIdx.y, bn = blockIdx.x;
  int tx = tid & 15, ty = tid >> 4;
  float acc[4][4] = {{0.f}};

  int arow = tid >> 2;            // 0..63 (m within tile)
  int akq = (tid & 3) << 2;       // 0,4,8,12 (k within tile)
  int gm_a = bm * 64 + arow;
  int bk = tid >> 4;              // 0..15 (k within tile)
  int bn0 = (tid & 15) << 2;      // n within tile

  int ntile = Kd >> 4;
  for (int kt = 0; kt < ntile; ++kt) {
    int k0a = (kt << 4) + akq;
    float4 av;
    if (a_mode == 0) {
      av = *(const float4*)&A[(size_t)gm_a * Kd + k0a];
      float m = mu[gm_a], r = rs[gm_a];
      float4 g4 = *(const float4*)&gam[k0a];
      float4 b4 = *(const float4*)&bet[k0a];
      av.x = (av.x - m) * r * g4.x + b4.x;
      av.y = (av.y - m) * r * g4.y + b4.y;
      av.z = (av.z - m) * r * g4.z + b4.z;
      av.w = (av.w - m) * r * g4.w + b4.w;
    } else {
      int bq = gm_a >> 9, sq = gm_a & 511;
      int hq = k0a >> 6, dd = k0a & 63;
      av = *(const float4*)&A[((((size_t)bq << 2) + hq) * 512 + sq) * 64 + dd];
    }
    As[akq + 0][arow] = av.x;
    As[akq + 1][arow] = av.y;
    As[akq + 2][arow] = av.z;
    As[akq + 3][arow] = av.w;
    *(float4*)&Bs[bk][bn0] =
        *(const float4*)&W[(size_t)((kt << 4) + bk) * N + bn * 64 + bn0];
    __syncthreads();
#pragma unroll
    for (int k = 0; k < 16; ++k) {
      float4 a4 = *(const float4*)&As[k][ty << 2];
      float4 b4 = *(const float4*)&Bs[k][tx << 2];
      float aa[4] = {a4.x, a4.y, a4.z, a4.w};
      float bb4[4] = {b4.x, b4.y, b4.z, b4.w};
#pragma unroll
      for (int i = 0; i < 4; ++i)
#pragma unroll
        for (int j = 0; j < 4; ++j) acc[i][j] = fmaf(aa[i], bb4[j], acc[i][j]);
    }
    __syncthreads();
  }

  int gm0 = bm * 64 + (ty << 2), gn0 = bn * 64 + (tx << 2);
  if (out_mode == 3) {
#pragma unroll
    for (int i = 0; i < 4; ++i)
      *(float4*)&out[(size_t)(gm0 + i) * N + gn0] =
          make_float4(acc[i][0], acc[i][1], acc[i][2], acc[i][3]);
  } else if (out_mode == 0) {
    int hq = gn0 >> 6, dd = gn0 & 63;
#pragma unroll
    for (int i = 0; i < 4; ++i) {
      int gm = gm0 + i;
      int bq = gm >> 9, sq = gm & 511;
      *(float4*)&out[((((size_t)bq << 2) + hq) * 512 + sq) * 64 + dd] =
          make_float4(acc[i][0], acc[i][1], acc[i][2], acc[i][3]);
    }
  } else if (out_mode == 1) {
#pragma unroll
    for (int j = 0; j < 4; ++j)
      *(float4*)&out[(size_t)(gn0 + j) * 8192 + gm0] =
          make_float4(acc[0][j], acc[1][j], acc[2][j], acc[3][j]);
  } else {  // out_mode == 2
    int hq = gn0 >> 6, dd = gn0 & 63;
#pragma unroll
    for (int i = 0; i < 4; ++i)
      *(float4*)&out[(((size_t)hq * 8192) + gm0 + i) * 64 + dd] =
          make_float4(acc[i][0], acc[i][1], acc[i][2], acc[i][3]);
  }
}

// ---------------- Fused Hopfield step ----------------
// One workgroup = 4 rows (s) of one (b,h). Scores live in registers
// (acc[4][32], n = 4*tid + 1024*j + e). Entmax tau via 16 bisections +
// one exact closed-form refinement. Weights -> LDS, then PV.
__global__ __launch_bounds__(256) void hopfield_step_kernel(
    const float* __restrict__ xi_in, const float* __restrict__ Kt,
    const float* __restrict__ V, const float* __restrict__ log_beta,
    float* __restrict__ xi_out) {
  __shared__ __align__(16) float w_lds[4 * 8192];  // 128KB weights
  __shared__ float xi_s[256];
  __shared__ __align__(16) float xacc[16 * 256];   // 16KB PV partials
  __shared__ float red[64];

  int tid = threadIdx.x;
  int bh = blockIdx.x & 7;       // XCD affinity: one (b,h) per XCD
  int tile = blockIdx.x >> 3;    // 0..127
  int h = bh & 3;
  size_t base_io = ((size_t)bh * 512 + tile * 4) * 64;  // bh = b*4+h

  xi_s[tid] = xi_in[base_io + tid];
  __syncthreads();

  float acc[4][32];
#pragma unroll
  for (int r = 0; r < 4; ++r)
#pragma unroll
    for (int i = 0; i < 32; ++i) acc[r][i] = 0.f;

  // Phase A: scores. Kt layout [256][8192], row = h*64+d.
  const float4* KtH = (const float4*)Kt + (size_t)h * 64 * 2048;
#pragma unroll 2
  for (int d = 0; d < 64; ++d) {
    float xv[4] = {xi_s[d], xi_s[64 + d], xi_s[128 + d], xi_s[192 + d]};
    const float4* kp = KtH + (size_t)d * 2048 + tid;
#pragma unroll
    for (int j = 0; j < 8; ++j) {
      float4 kv = kp[j << 8];
#pragma unroll
      for (int r = 0; r < 4; ++r) {
        acc[r][4 * j + 0] = fmaf(xv[r], kv.x, acc[r][4 * j + 0]);
        acc[r][4 * j + 1] = fmaf(xv[r], kv.y, acc[r][4 * j + 1]);
        acc[r][4 * j + 2] = fmaf(xv[r], kv.z, acc[r][4 * j + 2]);
        acc[r][4 * j + 3] = fmaf(xv[r], kv.w, acc[r][4 * j + 3]);
      }
    }
  }

  float beta = expf(log_beta[h]);
#pragma unroll
  for (int r = 0; r < 4; ++r)
#pragma unroll
    for (int i = 0; i < 32; ++i) acc[r][i] *= beta;

  int wid = tid >> 6, lane = tid & 63;

  // Phase B1: per-row max
  float mx[4];
#pragma unroll
  for (int r = 0; r < 4; ++r) {
    float m = acc[r][0];
#pragma unroll
    for (int i = 1; i < 32; ++i) m = fmaxf(m, acc[r][i]);
    mx[r] = wred_max(m);
  }
  if (lane == 0) {
#pragma unroll
    for (int r = 0; r < 4; ++r) red[wid * 4 + r] = mx[r];
  }
  __syncthreads();
#pragma unroll
  for (int r = 0; r < 4; ++r)
    mx[r] = fmaxf(fmaxf(red[r], red[4 + r]), fmaxf(red[8 + r], red[12 + r]));
  __syncthreads();

  // y = (x - max) / 2
#pragma unroll
  for (int r = 0; r < 4; ++r)
#pragma unroll
    for (int i = 0; i < 32; ++i) acc[r][i] = (acc[r][i] - mx[r]) * 0.5f;

  // Phase B2: bisection for tau in [-1, 0]; f(tau)=sum(max(y-tau,0)^2) dec.
  float lo[4] = {-1.f, -1.f, -1.f, -1.f}, hi[4] = {0.f, 0.f, 0.f, 0.f};
#pragma unroll 1
  for (int it = 0; it < 16; ++it) {
    float tv[4], fs[4];
#pragma unroll
    for (int r = 0; r < 4; ++r) {
      tv[r] = 0.5f * (lo[r] + hi[r]);
      float f = 0.f;
#pragma unroll
      for (int i = 0; i < 32; ++i) {
        float t = fmaxf(acc[r][i] - tv[r], 0.f);
        f = fmaf(t, t, f);
      }
      fs[r] = wred_add(f);
    }
    if (lane == 0) {
#pragma unroll
      for (int r = 0; r < 4; ++r) red[wid * 4 + r] = fs[r];
    }
    __syncthreads();
#pragma unroll
    for (int r = 0; r < 4; ++r) {
      float tot = red[r] + red[4 + r] + red[8 + r] + red[12 + r];
      if (tot >= 1.f) lo[r] = tv[r]; else hi[r] = tv[r];
    }
    __syncthreads();
  }

  // Phase B3: exact refinement over support {y > lo}
  float tau[4];
  {
    float kc[4], s1[4], s2[4];
#pragma unroll
    for (int r = 0; r < 4; ++r) {
      float kk = 0.f, a = 0.f, q = 0.f;
#pragma unroll
      for (int i = 0; i < 32; ++i) {
        float y = acc[r][i];
        if (y > lo[r]) { kk += 1.f; a += y; q = fmaf(y, y, q); }
      }
      kc[r] = wred_add(kk);
      s1[r] = wred_add(a);
      s2[r] = wred_add(q);
    }
    if (lane == 0) {
#pragma unroll
      for (int r = 0; r < 4; ++r) {
        red[wid * 12 + r * 3 + 0] = kc[r];
        red[wid * 12 + r * 3 + 1] = s1[r];
        red[wid * 12 + r * 3 + 2] = s2[r];
      }
    }
    __syncthreads();
#pragma unroll
    for (int r = 0; r < 4; ++r) {
      float K = 0.f, S1 = 0.f, S2 = 0.f;
#pragma unroll
      for (int w = 0; w < 4; ++w) {
        K += red[w * 12 + r * 3 + 0];
        S1 += red[w * 12 + r * 3 + 1];
        S2 += red[w * 12 + r * 3 + 2];
      }
      float mean = S1 / K;
      float ss = S2 - mean * S1;
      float delta = (1.f - ss) / K;
      tau[r] = (delta > 0.f) ? (mean - sqrtf(delta)) : mean;
    }
  }

  // weights -> LDS (w = max(y - tau, 0)^2)
#pragma unroll
  for (int r = 0; r < 4; ++r) {
#pragma unroll
    for (int j = 0; j < 8; ++j) {
      float4 wv;
      float t0 = fmaxf(acc[r][4 * j + 0] - tau[r], 0.f);
      float t1 = fmaxf(acc[r][4 * j + 1] - tau[r], 0.f);
      float t2 = fmaxf(acc[r][4 * j + 2] - tau[r], 0.f);
      float t3 = fmaxf(acc[r][4 * j + 3] - tau[r], 0.f);
      wv.x = t0 * t0; wv.y = t1 * t1; wv.z = t2 * t2; wv.w = t3 * t3;
      ((float4*)w_lds)[r * 2048 + tid + (j << 8)] = wv;
    }
  }
  __syncthreads();

  // Phase C: xi_new = w @ V.  V layout [H][8192][64].
  int part = tid >> 4;   // 0..15, each owns 512 n
  int dq = tid & 15;     // d = dq*4 .. +3
  const float4* Vh = (const float4*)V + (size_t)h * 8192 * 16;
  const float4* W4 = (const float4*)w_lds;
  float4 a0 = {0.f, 0.f, 0.f, 0.f}, a1 = a0, a2 = a0, a3 = a0;
  int nb = part * 128;  // float4-chunk base
#pragma unroll 2
  for (int c = 0; c < 128; ++c) {
    float4 w0 = W4[nb + c];
    float4 w1 = W4[2048 + nb + c];
    float4 w2 = W4[4096 + nb + c];
    float4 w3 = W4[6144 + nb + c];
    float w0a[4] = {w0.x, w0.y, w0.z, w0.w};
    float w1a[4] = {w1.x, w1.y, w1.z, w1.w};
    float w2a[4] = {w2.x, w2.y, w2.z, w2.w};
    float w3a[4] = {w3.x, w3.y, w3.z, w3.w};
    int n = (nb + c) << 2;
#pragma unroll
    for (int e = 0; e < 4; ++e) {
      float4 v4 = Vh[(size_t)(n + e) * 16 + dq];
      a0.x = fmaf(w0a[e], v4.x, a0.x); a0.y = fmaf(w0a[e], v4.y, a0.y);
      a0.z = fmaf(w0a[e], v4.z, a0.z); a0.w = fmaf(w0a[e], v4.w, a0.w);
      a1.x = fmaf(w1a[e], v4.x, a1.x); a1.y = fmaf(w1a[e], v4.y, a1.y);
      a1.z = fmaf(w1a[e], v4.z, a1.z); a1.w = fmaf(w1a[e], v4.w, a1.w);
      a2.x = fmaf(w2a[e], v4.x, a2.x); a2.y = fmaf(w2a[e], v4.y, a2.y);
      a2.z = fmaf(w2a[e], v4.z, a2.z); a2.w = fmaf(w2a[e], v4.w, a2.w);
      a3.x = fmaf(w3a[e], v4.x, a3.x); a3.y = fmaf(w3a[e], v4.y, a3.y);
      a3.z = fmaf(w3a[e], v4.z, a3.z); a3.w = fmaf(w3a[e], v4.w, a3.w);
    }
  }
  *(float4*)&xacc[part * 256 + 0 * 64 + (dq << 2)] = a0;
  *(float4*)&xacc[part * 256 + 1 * 64 + (dq << 2)] = a1;
  *(float4*)&xacc[part * 256 + 2 * 64 + (dq << 2)] = a2;
  *(float4*)&xacc[part * 256 + 3 * 64 + (dq << 2)] = a3;
  __syncthreads();
  {
    float s = 0.f;
#pragma unroll
    for (int p = 0; p < 16; ++p) s += xacc[p * 256 + tid];
    xi_out[base_io + tid] = s;  // tid = r*64 + d
  }
}

// ---------------- converged copy: [B][H][S][D] -> [B][S][H*D] ----------------
__global__ __launch_bounds__(256) void conv_copy_kernel(
    const float* __restrict__ xi, float* __restrict__ out) {
  int o4 = blockIdx.x * 256 + threadIdx.x;
  int o = o4 << 2;
  int dd = o & 63, hq = (o >> 6) & 3, sq = (o >> 8) & 511, bq = o >> 17;
  float4 v =
      *(const float4*)&xi[((((size_t)bq << 2) + hq) * 512 + sq) * 64 + dd];
  *(float4*)&out[o] = v;
}

extern "C" void kernel_launch(void* const* d_in, const int* in_sizes, int n_in,
                              void* d_out, int out_size, void* d_ws,
                              size_t ws_size, hipStream_t stream) {
  (void)in_sizes; (void)n_in; (void)out_size; (void)ws_size;
  const float* hidden = (const float*)d_in[0];
  const float* memory = (const float*)d_in[1];
  const float* Wq = (const float*)d_in[2];
  const float* Wk = (const float*)d_in[3];
  const float* Wv = (const float*)d_in[4];
  const float* Wo = (const float*)d_in[5];
  const float* log_beta = (const float*)d_in[6];
  const float* g_s = (const float*)d_in[7];
  const float* b_s = (const float*)d_in[8];
  const float* g_m = (const float*)d_in[9];
  const float* b_m = (const float*)d_in[10];
  float* out = (float*)d_out;

  float* ws = (float*)d_ws;
  float* mu_h = ws;                     // 1024
  float* rs_h = ws + 1024;              // 1024
  float* mu_m = ws + 2048;              // 8192
  float* rs_m = ws + 10240;             // 8192
  float* xiA = ws + 18432;              // 262144
  float* xiB = xiA + 262144;            // 262144
  float* Kt = xiB + 262144;             // 2097152  [256][8192]
  float* Vv = Kt + 2097152;             // 2097152  [4][8192][64]

  ln_stats_kernel<<<1024, 256, 0, stream>>>(hidden, 2048, mu_h, rs_h);
  ln_stats_kernel<<<8192, 256, 0, stream>>>(memory, 1024, mu_m, rs_m);

  // Q -> xiA (xi layout)
  gemm_ln_kernel<<<dim3(4, 16), 256, 0, stream>>>(
      hidden, Wq, mu_h, rs_h, g_s, b_s, xiA, 1024, 2048, 256, 0, 0);
  // K^T
  gemm_ln_kernel<<<dim3(4, 128), 256, 0, stream>>>(
      memory, Wk, mu_m, rs_m, g_m, b_m, Kt, 8192, 1024, 256, 0, 1);
  // V
  gemm_ln_kernel<<<dim3(4, 128), 256, 0, stream>>>(
      memory, Wv, mu_m, rs_m, g_m, b_m, Vv, 8192, 1024, 256, 0, 2);

  hopfield_step_kernel<<<1024, 256, 0, stream>>>(xiA, Kt, Vv, log_beta, xiB);
  hopfield_step_kernel<<<1024, 256, 0, stream>>>(xiB, Kt, Vv, log_beta, xiA);
  hopfield_step_kernel<<<1024, 256, 0, stream>>>(xiA, Kt, Vv, log_beta, xiB);

  // output = converged @ Wo
  gemm_ln_kernel<<<dim3(32, 16), 256, 0, stream>>>(
      xiB, Wo, nullptr, nullptr, nullptr, nullptr, out, 1024, 256, 2048, 1, 3);
  // converged
  conv_copy_kernel<<<256, 256, 0, stream>>>(xiB, out + 2097152);
}

// Round 3
// 671.833 us; speedup vs baseline: 1.7710x; 1.7710x over previous
//
#include <hip/hip_runtime.h>
#include <math.h>

typedef _Float16 f16;
typedef f16 f16x8 __attribute__((ext_vector_type(8)));
typedef float f32x4 __attribute__((ext_vector_type(4)));

#define QSCALE 32768.0f
#define QINV 3.0517578125e-5f
#define QOFF 1.5f

__device__ __forceinline__ float wred_add(float v) {
#pragma unroll
  for (int off = 32; off >= 1; off >>= 1) v += __shfl_xor(v, off, 64);
  return v;
}

// ---------------- LayerNorm row stats ----------------
__global__ __launch_bounds__(256) void ln_stats_kernel(
    const float* __restrict__ X, int cols, float* __restrict__ mu,
    float* __restrict__ rs) {
  int row = blockIdx.x, tid = threadIdx.x;
  const float4* xr = (const float4*)(X + (size_t)row * cols);
  int nv = cols >> 10;
  float s = 0.f, s2 = 0.f;
  for (int v = 0; v < nv; ++v) {
    float4 x4 = xr[tid + (v << 8)];
    s += x4.x + x4.y + x4.z + x4.w;
    s2 += x4.x * x4.x + x4.y * x4.y + x4.z * x4.z + x4.w * x4.w;
  }
  s = wred_add(s);
  s2 = wred_add(s2);
  __shared__ float rb[8];
  int wid = tid >> 6, lane = tid & 63;
  if (lane == 0) { rb[wid] = s; rb[4 + wid] = s2; }
  __syncthreads();
  if (tid == 0) {
    float S = rb[0] + rb[1] + rb[2] + rb[3];
    float S2 = rb[4] + rb[5] + rb[6] + rb[7];
    float m = S / (float)cols;
    float var = S2 / (float)cols - m * m;
    mu[row] = m;
    rs[row] = 1.f / sqrtf(var + 1e-5f);
  }
}

// ---------------- Generic f32 tiled GEMM: C = LN(A) @ W ----------------
// a_mode: 0 = row-major A with fused LN; 1 = A in xi layout [B][H][S][D]
// out_mode: 0 = xi layout; 3 = row-major;
//           4 = split-fp16 K pack (out16a=Khi, out16b=Klo*512)
//           5 = fp16 V pack (out16a=Vp)
__global__ __launch_bounds__(256) void gemm_ln_kernel(
    const float* __restrict__ A, const float* __restrict__ W,
    const float* __restrict__ mu, const float* __restrict__ rs,
    const float* __restrict__ gam, const float* __restrict__ bet,
    float* __restrict__ out, f16x8* __restrict__ out16a,
    f16x8* __restrict__ out16b, int M, int Kd, int N, int a_mode,
    int out_mode) {
  __shared__ __align__(16) float As[16][64];
  __shared__ __align__(16) float Bs[16][64];
  __shared__ __align__(16) float Ts[64][68];
  int tid = threadIdx.x;
  int bm = blockIdx.y, bn = blockIdx.x;
  int tx = tid & 15, ty = tid >> 4;
  float acc[4][4] = {{0.f}};

  int arow = tid >> 2;
  int akq = (tid & 3) << 2;
  int gm_a = bm * 64 + arow;
  int bk = tid >> 4;
  int bn0 = (tid & 15) << 2;

  int ntile = Kd >> 4;
  for (int kt = 0; kt < ntile; ++kt) {
    int k0a = (kt << 4) + akq;
    float4 av;
    if (a_mode == 0) {
      av = *(const float4*)&A[(size_t)gm_a * Kd + k0a];
      float m = mu[gm_a], r = rs[gm_a];
      float4 g4 = *(const float4*)&gam[k0a];
      float4 b4 = *(const float4*)&bet[k0a];
      av.x = (av.x - m) * r * g4.x + b4.x;
      av.y = (av.y - m) * r * g4.y + b4.y;
      av.z = (av.z - m) * r * g4.z + b4.z;
      av.w = (av.w - m) * r * g4.w + b4.w;
    } else {
      int bq = gm_a >> 9, sq = gm_a & 511;
      int hq = k0a >> 6, dd = k0a & 63;
      av = *(const float4*)&A[((((size_t)bq << 2) + hq) * 512 + sq) * 64 + dd];
    }
    As[akq + 0][arow] = av.x;
    As[akq + 1][arow] = av.y;
    As[akq + 2][arow] = av.z;
    As[akq + 3][arow] = av.w;
    *(float4*)&Bs[bk][bn0] =
        *(const float4*)&W[(size_t)((kt << 4) + bk) * N + bn * 64 + bn0];
    __syncthreads();
#pragma unroll
    for (int k = 0; k < 16; ++k) {
      float4 a4 = *(const float4*)&As[k][ty << 2];
      float4 b4 = *(const float4*)&Bs[k][tx << 2];
      float aa[4] = {a4.x, a4.y, a4.z, a4.w};
      float bb4[4] = {b4.x, b4.y, b4.z, b4.w};
#pragma unroll
      for (int i = 0; i < 4; ++i)
#pragma unroll
        for (int j = 0; j < 4; ++j) acc[i][j] = fmaf(aa[i], bb4[j], acc[i][j]);
    }
    __syncthreads();
  }

  int gm0 = bm * 64 + (ty << 2), gn0 = bn * 64 + (tx << 2);
  if (out_mode == 3) {
#pragma unroll
    for (int i = 0; i < 4; ++i)
      *(float4*)&out[(size_t)(gm0 + i) * N + gn0] =
          make_float4(acc[i][0], acc[i][1], acc[i][2], acc[i][3]);
  } else if (out_mode == 0) {
    int hq = gn0 >> 6, dd = gn0 & 63;
#pragma unroll
    for (int i = 0; i < 4; ++i) {
      int gm = gm0 + i;
      int bq = gm >> 9, sq = gm & 511;
      *(float4*)&out[((((size_t)bq << 2) + hq) * 512 + sq) * 64 + dd] =
          make_float4(acc[i][0], acc[i][1], acc[i][2], acc[i][3]);
    }
  } else {
    // stage tile to LDS: Ts[key_local][d]
#pragma unroll
    for (int i = 0; i < 4; ++i)
      *(float4*)&Ts[(ty << 2) + i][tx << 2] =
          make_float4(acc[i][0], acc[i][1], acc[i][2], acc[i][3]);
    __syncthreads();
    if (out_mode == 4) {
      // Khi/Klo: [((h*512+kt)*2+dc)*64 + l][j] = K[kt*16+(l&15)][dc*32+(l>>4)*8+j]
#pragma unroll
      for (int i = 0; i < 2; ++i) {
        int slot = tid + (i << 8);
        int blk = slot >> 6, l = slot & 63;
        int ktl = blk >> 1, dc = blk & 1;
        int key = (ktl << 4) + (l & 15);
        int db = (dc << 5) + ((l >> 4) << 3);
        f16x8 hi, lo;
#pragma unroll
        for (int j = 0; j < 8; ++j) {
          float v = Ts[key][db + j];
          f16 hv = (f16)v;
          hi[j] = hv;
          lo[j] = (f16)((v - (float)hv) * 512.f);
        }
        size_t o = (((size_t)(bn * 512 + bm * 4 + ktl) * 2 + dc) << 6) + l;
        out16a[o] = hi;
        out16b[o] = lo;
      }
    } else {
      // Vp: [((h*4+dt)*256+kc)*64 + l][j] = V[kc*32+(l>>4)*8+j][dt*16+(l&15)]
#pragma unroll
      for (int i = 0; i < 2; ++i) {
        int slot = tid + (i << 8);
        int blk = slot >> 6, l = slot & 63;
        int dt = blk >> 1, kcl = blk & 1;
        int keyb = (kcl << 5) + ((l >> 4) << 3);
        int d = (dt << 4) + (l & 15);
        f16x8 v8;
#pragma unroll
        for (int j = 0; j < 8; ++j) v8[j] = (f16)Ts[keyb + j][d];
        size_t o = (((size_t)(bn * 4 + dt) * 256 + bm * 2 + kcl) << 6) + l;
        out16a[o] = v8;
      }
    }
  }
}

// ---------------- S1: precise scores -> u16 y to global ----------------
// WG = 16 queries x 8192 keys; wave w owns key-tiles [w*64, w*64+64).
__global__ __launch_bounds__(512) void hop_score_kernel(
    const float* __restrict__ xi_in, const f16x8* __restrict__ Khi,
    const f16x8* __restrict__ Klo, const float* __restrict__ log_beta,
    unsigned short* __restrict__ Y) {
  __shared__ float xiq[16][64];
  __shared__ float mxb[8][16];
  __shared__ float mxs[16];
  const int tid = threadIdx.x;
  const int w = tid >> 6, l = tid & 63;
  const int ql = l & 15, g = l >> 4;
  const int bh = blockIdx.x & 7, qtile = blockIdx.x >> 3;
  const int h = bh & 3;
  const size_t base_io = ((size_t)bh * 512 + qtile * 16) * 64;

  float beta = expf(log_beta[h]);
  for (int i = tid; i < 1024; i += 512)
    xiq[i >> 6][i & 63] = xi_in[base_io + i] * beta;
  __syncthreads();

  f16x8 xh0, xh1, xl0, xl1;
#pragma unroll
  for (int j = 0; j < 8; ++j) {
    float x0 = xiq[ql][(g << 3) + j];
    float x1 = xiq[ql][32 + (g << 3) + j];
    f16 h0 = (f16)x0, h1 = (f16)x1;
    xh0[j] = h0; xl0[j] = (f16)((x0 - (float)h0) * 512.f);
    xh1[j] = h1; xl1[j] = (f16)((x1 - (float)h1) * 512.f);
  }

  const f16x8* kb = Khi + (size_t)h * 65536 + l;
  const f16x8* kl = Klo + (size_t)h * 65536 + l;
  const int kt0 = w * 64;

  // Pass A1: approximate per-row max (hi*hi only; shift-invariance)
  float mymax = -3.4e38f;
  for (int kt = kt0; kt < kt0 + 64; ++kt) {
    f32x4 c = {0.f, 0.f, 0.f, 0.f};
    c = __builtin_amdgcn_mfma_f32_16x16x32_f16(kb[(size_t)kt * 128], xh0, c, 0, 0, 0);
    c = __builtin_amdgcn_mfma_f32_16x16x32_f16(kb[(size_t)kt * 128 + 64], xh1, c, 0, 0, 0);
    mymax = fmaxf(fmaxf(fmaxf(c[0], c[1]), fmaxf(c[2], c[3])), mymax);
  }
  mymax = fmaxf(mymax, __shfl_xor(mymax, 16, 64));
  mymax = fmaxf(mymax, __shfl_xor(mymax, 32, 64));
  if (l < 16) mxb[w][ql] = mymax;
  __syncthreads();
  if (tid < 16) {
    float m = mxb[0][tid];
#pragma unroll
    for (int ww = 1; ww < 8; ++ww) m = fmaxf(m, mxb[ww][tid]);
    mxs[tid] = m;
  }
  __syncthreads();
  const float mh = mxs[ql] * 0.5f;

  // Pass A2: split-precision scores, quantize to u16, store
  const size_t Ybase = (size_t)(bh * 32 + qtile) * 131072;
  for (int kt = kt0; kt < kt0 + 64; ++kt) {
    f16x8 a0 = kb[(size_t)kt * 128], a1 = kb[(size_t)kt * 128 + 64];
    f16x8 b0 = kl[(size_t)kt * 128], b1 = kl[(size_t)kt * 128 + 64];
    f32x4 cm = {0.f, 0.f, 0.f, 0.f}, cx = {0.f, 0.f, 0.f, 0.f};
    cm = __builtin_amdgcn_mfma_f32_16x16x32_f16(a0, xh0, cm, 0, 0, 0);
    cm = __builtin_amdgcn_mfma_f32_16x16x32_f16(a1, xh1, cm, 0, 0, 0);
    cx = __builtin_amdgcn_mfma_f32_16x16x32_f16(b0, xh0, cx, 0, 0, 0);
    cx = __builtin_amdgcn_mfma_f32_16x16x32_f16(a0, xl0, cx, 0, 0, 0);
    cx = __builtin_amdgcn_mfma_f32_16x16x32_f16(b1, xh1, cx, 0, 0, 0);
    cx = __builtin_amdgcn_mfma_f32_16x16x32_f16(a1, xl1, cx, 0, 0, 0);
    ushort4 uv;
    unsigned short* up = (unsigned short*)&uv;
#pragma unroll
    for (int r = 0; r < 4; ++r) {
      float s = fmaf(cx[r], 0.001953125f, cm[r]);
      float y = fmaf(s, 0.5f, -mh);
      float uq = fmaf(y, QSCALE, QOFF * QSCALE + 0.5f);
      uq = fminf(fmaxf(uq, 0.f), 65535.f);
      up[r] = (unsigned short)(int)uq;
    }
    *(ushort4*)&Y[Ybase + (size_t)(kt >> 1) * 512 + ql * 32 + (kt & 1) * 16 +
                  (g << 2)] = uv;
  }
}

// ---------------- S2: exact entmax tau per row ----------------
__global__ __launch_bounds__(256) void hop_tau_kernel(
    const unsigned short* __restrict__ Y, float* __restrict__ tau) {
  const int row = blockIdx.x;  // bh*512 + q
  const int bh = row >> 9, qi = row & 511;
  const int qtile = qi >> 4, ql = qi & 15;
  const size_t yb = (size_t)(bh * 32 + qtile) * 131072 + ql * 32;
  const int t = threadIdx.x;
  const uint4* p = (const uint4*)(Y + yb + (size_t)t * 512);
  float y[32];
#pragma unroll
  for (int v = 0; v < 4; ++v) {
    uint4 u = p[v];
    unsigned a[4] = {u.x, u.y, u.z, u.w};
#pragma unroll
    for (int e = 0; e < 4; ++e) {
      y[v * 8 + e * 2] = fmaf((float)(a[e] & 0xffffu), QINV, -QOFF);
      y[v * 8 + e * 2 + 1] = fmaf((float)(a[e] >> 16), QINV, -QOFF);
    }
  }
  __shared__ float rb[4];
  __shared__ float rb3[4][3];
  float lo = -1.1f, hi = 0.1f;
  const int wi = t >> 6, lane = t & 63;
#pragma unroll 1
  for (int it = 0; it < 16; ++it) {
    float tv = 0.5f * (lo + hi);
    float f = 0.f;
#pragma unroll
    for (int i = 0; i < 32; ++i) {
      float d = fmaxf(y[i] - tv, 0.f);
      f = fmaf(d, d, f);
    }
    f = wred_add(f);
    if (lane == 0) rb[wi] = f;
    __syncthreads();
    float tot = rb[0] + rb[1] + rb[2] + rb[3];
    if (tot >= 1.f) lo = tv; else hi = tv;
    __syncthreads();
  }
  float kk = 0.f, s1 = 0.f, s2 = 0.f;
#pragma unroll
  for (int i = 0; i < 32; ++i) {
    if (y[i] > lo) { kk += 1.f; s1 += y[i]; s2 = fmaf(y[i], y[i], s2); }
  }
  kk = wred_add(kk);
  s1 = wred_add(s1);
  s2 = wred_add(s2);
  if (lane == 0) { rb3[wi][0] = kk; rb3[wi][1] = s1; rb3[wi][2] = s2; }
  __syncthreads();
  if (t == 0) {
    float K = 0.f, S1 = 0.f, S2 = 0.f;
#pragma unroll
    for (int ww = 0; ww < 4; ++ww) {
      K += rb3[ww][0]; S1 += rb3[ww][1]; S2 += rb3[ww][2];
    }
    float mean = S1 / K;
    float ss = fmaf(-mean, S1, S2);
    float delta = (1.f - ss) / K;
    tau[row] = delta > 0.f ? mean - sqrtf(delta) : mean;
  }
}

// ---------------- S3: weights (p^2 in f32, once-rounded f16) + PV MFMA ----------------
__global__ __launch_bounds__(512) void hop_pv_kernel(
    const unsigned short* __restrict__ Y, const f16x8* __restrict__ Vp,
    const float* __restrict__ tau, float* __restrict__ xi_out) {
  __shared__ float outp[8][16][64];
  __shared__ float taus[16];
  const int tid = threadIdx.x;
  const int w = tid >> 6, l = tid & 63;
  const int ql = l & 15, g = l >> 4;
  const int bh = blockIdx.x & 7, qtile = blockIdx.x >> 3;
  const int h = bh & 3;
  const size_t base_io = ((size_t)bh * 512 + qtile * 16) * 64;

  if (tid < 16) taus[tid] = tau[bh * 512 + qtile * 16 + tid];
  __syncthreads();
  const float t1 = taus[ql];
  const size_t Ybase = (size_t)(bh * 32 + qtile) * 131072;
  const f16x8* vb = Vp + (size_t)h * 65536 + l;

  f32x4 m2[4];
#pragma unroll
  for (int dt = 0; dt < 4; ++dt) m2[dt] = (f32x4){0.f, 0.f, 0.f, 0.f};

  for (int kc = 0; kc < 32; ++kc) {
    const int chunk = w * 32 + kc;
    uint4 uv = *(const uint4*)(Y + Ybase + (size_t)chunk * 512 + ql * 32 +
                               (g << 3));
    unsigned a[4] = {uv.x, uv.y, uv.z, uv.w};
    f16x8 a2;
#pragma unroll
    for (int e = 0; e < 4; ++e) {
      float y0 = fmaf((float)(a[e] & 0xffffu), QINV, -QOFF);
      float y1 = fmaf((float)(a[e] >> 16), QINV, -QOFF);
      float p0 = fmaxf(y0 - t1, 0.f);
      float p1 = fmaxf(y1 - t1, 0.f);
      a2[e * 2] = (f16)(p0 * p0);
      a2[e * 2 + 1] = (f16)(p1 * p1);
    }
#pragma unroll
    for (int dt = 0; dt < 4; ++dt) {
      f16x8 vf = vb[(((size_t)dt * 256 + chunk) << 6)];
      m2[dt] = __builtin_amdgcn_mfma_f32_16x16x32_f16(a2, vf, m2[dt], 0, 0, 0);
    }
  }
#pragma unroll
  for (int dt = 0; dt < 4; ++dt)
#pragma unroll
    for (int r = 0; r < 4; ++r)
      outp[w][(g << 2) + r][dt * 16 + ql] = m2[dt][r];
  __syncthreads();
  for (int i = tid; i < 1024; i += 512) {
    float s = 0.f;
#pragma unroll
    for (int ww = 0; ww < 8; ++ww) s += outp[ww][i >> 6][i & 63];
    xi_out[base_io + i] = s;
  }
}

// ---------------- converged copy ----------------
__global__ __launch_bounds__(256) void conv_copy_kernel(
    const float* __restrict__ xi, float* __restrict__ out) {
  int o4 = blockIdx.x * 256 + threadIdx.x;
  int o = o4 << 2;
  int dd = o & 63, hq = (o >> 6) & 3, sq = (o >> 8) & 511, bq = o >> 17;
  float4 v =
      *(const float4*)&xi[((((size_t)bq << 2) + hq) * 512 + sq) * 64 + dd];
  *(float4*)&out[o] = v;
}

extern "C" void kernel_launch(void* const* d_in, const int* in_sizes, int n_in,
                              void* d_out, int out_size, void* d_ws,
                              size_t ws_size, hipStream_t stream) {
  (void)in_sizes; (void)n_in; (void)out_size; (void)ws_size;
  const float* hidden = (const float*)d_in[0];
  const float* memory = (const float*)d_in[1];
  const float* Wq = (const float*)d_in[2];
  const float* Wk = (const float*)d_in[3];
  const float* Wv = (const float*)d_in[4];
  const float* Wo = (const float*)d_in[5];
  const float* log_beta = (const float*)d_in[6];
  const float* g_s = (const float*)d_in[7];
  const float* b_s = (const float*)d_in[8];
  const float* g_m = (const float*)d_in[9];
  const float* b_m = (const float*)d_in[10];
  float* out = (float*)d_out;

  float* ws = (float*)d_ws;
  float* mu_h = ws;                   // 1024
  float* rs_h = ws + 1024;            // 1024
  float* mu_m = ws + 2048;            // 8192
  float* rs_m = ws + 10240;           // 8192
  float* xiA = ws + 18432;            // 262144
  float* xiB = xiA + 262144;          // 262144
  f16x8* Khi = (f16x8*)(xiB + 262144);          // 4 MB
  f16x8* Klo = Khi + 262144;                    // 4 MB
  f16x8* Vp = Klo + 262144;                     // 4 MB
  unsigned short* Y = (unsigned short*)(Vp + 262144);  // 64 MB
  float* tau = (float*)(Y + 33554432);          // 16 KB

  ln_stats_kernel<<<1024, 256, 0, stream>>>(hidden, 2048, mu_h, rs_h);
  ln_stats_kernel<<<8192, 256, 0, stream>>>(memory, 1024, mu_m, rs_m);

  // Q -> xiA (f32, xi layout)
  gemm_ln_kernel<<<dim3(4, 16), 256, 0, stream>>>(
      hidden, Wq, mu_h, rs_h, g_s, b_s, xiA, nullptr, nullptr, 1024, 2048, 256,
      0, 0);
  // K -> Khi/Klo (split fp16, MFMA A-frag layout)
  gemm_ln_kernel<<<dim3(4, 128), 256, 0, stream>>>(
      memory, Wk, mu_m, rs_m, g_m, b_m, nullptr, Khi, Klo, 8192, 1024, 256, 0,
      4);
  // V -> Vp (fp16, MFMA B-frag layout)
  gemm_ln_kernel<<<dim3(4, 128), 256, 0, stream>>>(
      memory, Wv, mu_m, rs_m, g_m, b_m, nullptr, Vp, nullptr, 8192, 1024, 256,
      0, 5);

  float* xin = xiA;
  float* xout = xiB;
  for (int step = 0; step < 3; ++step) {
    hop_score_kernel<<<256, 512, 0, stream>>>(xin, Khi, Klo, log_beta, Y);
    hop_tau_kernel<<<4096, 256, 0, stream>>>(Y, tau);
    hop_pv_kernel<<<256, 512, 0, stream>>>(Y, Vp, tau, xout);
    float* t = xin; xin = xout; xout = t;
  }
  // xin now holds converged (xiB after 3 swaps)

  gemm_ln_kernel<<<dim3(32, 16), 256, 0, stream>>>(
      xin, Wo, nullptr, nullptr, nullptr, nullptr, out, nullptr, nullptr, 1024,
      256, 2048, 1, 3);
  conv_copy_kernel<<<256, 256, 0, stream>>>(xin, out + 2097152);
}

// Round 4
// 541.547 us; speedup vs baseline: 2.1970x; 1.2406x over previous
//
#include <hip/hip_runtime.h>
#include <math.h>

typedef _Float16 f16;
typedef f16 f16x8 __attribute__((ext_vector_type(8)));
typedef float f32x4 __attribute__((ext_vector_type(4)));

#define QSCALE 32768.0f
#define QINV 3.0517578125e-5f
#define QOFF 1.5f

__device__ __forceinline__ float wred_add(float v) {
#pragma unroll
  for (int off = 32; off >= 1; off >>= 1) v += __shfl_xor(v, off, 64);
  return v;
}

// ---------------- LayerNorm row stats ----------------
__global__ __launch_bounds__(256) void ln_stats_kernel(
    const float* __restrict__ X, int cols, float* __restrict__ mu,
    float* __restrict__ rs) {
  int row = blockIdx.x, tid = threadIdx.x;
  const float4* xr = (const float4*)(X + (size_t)row * cols);
  int nv = cols >> 10;
  float s = 0.f, s2 = 0.f;
  for (int v = 0; v < nv; ++v) {
    float4 x4 = xr[tid + (v << 8)];
    s += x4.x + x4.y + x4.z + x4.w;
    s2 += x4.x * x4.x + x4.y * x4.y + x4.z * x4.z + x4.w * x4.w;
  }
  s = wred_add(s);
  s2 = wred_add(s2);
  __shared__ float rb[8];
  int wid = tid >> 6, lane = tid & 63;
  if (lane == 0) { rb[wid] = s; rb[4 + wid] = s2; }
  __syncthreads();
  if (tid == 0) {
    float S = rb[0] + rb[1] + rb[2] + rb[3];
    float S2 = rb[4] + rb[5] + rb[6] + rb[7];
    float m = S / (float)cols;
    float var = S2 / (float)cols - m * m;
    mu[row] = m;
    rs[row] = 1.f / sqrtf(var + 1e-5f);
  }
}

// ---------------- split A into hi/lo f16 MFMA A-fragments ----------------
// Apack block blk = kc*(M/16)+mt; lane l elem j <-> (m = mt*16+(l&15),
// k = kc*32+(l>>4)*8+j).  A = (X - mu)*rs.  lay: 0 row-major, 1 xi-layout.
__global__ __launch_bounds__(256) void split_a_kernel(
    const float* __restrict__ X, const float* __restrict__ mu,
    const float* __restrict__ rs, f16x8* __restrict__ Ah,
    f16x8* __restrict__ Al, int M, int Kd, int lay) {
  int blk = blockIdx.x * 4 + (threadIdx.x >> 6);
  int l = threadIdx.x & 63;
  int nmt = M >> 4;
  int kc = blk / nmt, mt = blk - kc * nmt;
  int m = mt * 16 + (l & 15);
  int k = kc * 32 + ((l >> 4) << 3);
  const float* src;
  if (lay == 0) {
    src = X + (size_t)m * Kd + k;
  } else {
    int b = m >> 9, s = m & 511, hh = k >> 6, d = k & 63;
    src = X + ((((size_t)b * 4 + hh) * 512 + s) << 6) + d;
  }
  float mm = mu ? mu[m] : 0.f;
  float rr = rs ? rs[m] : 1.f;
  f16x8 hi, lo;
#pragma unroll
  for (int j = 0; j < 8; ++j) {
    float v = (src[j] - mm) * rr;
    f16 hv = (f16)v;
    hi[j] = hv;
    lo[j] = (f16)((v - (float)hv) * 512.f);
  }
  size_t o = ((size_t)blk << 6) + l;
  Ah[o] = hi;
  Al[o] = lo;
}

// ---------------- split W into hi/lo f16 MFMA B-fragments ----------------
// Bpack block blk = kc*(N/16)+nt; lane l elem j <-> (n = nt*16+(l&15),
// k = kc*32+(l>>4)*8+j).  W' = diag(g)*W.
__global__ __launch_bounds__(256) void split_w_kernel(
    const float* __restrict__ W, const float* __restrict__ g,
    f16x8* __restrict__ Bh, f16x8* __restrict__ Bl, int Kd, int N) {
  int blk = blockIdx.x * 4 + (threadIdx.x >> 6);
  int l = threadIdx.x & 63;
  int nnt = N >> 4;
  int kc = blk / nnt, nt = blk - kc * nnt;
  int n = nt * 16 + (l & 15);
  int k0 = kc * 32 + ((l >> 4) << 3);
  f16x8 hi, lo;
#pragma unroll
  for (int j = 0; j < 8; ++j) {
    float v = W[(size_t)(k0 + j) * N + n];
    if (g) v *= g[k0 + j];
    f16 hv = (f16)v;
    hi[j] = hv;
    lo[j] = (f16)((v - (float)hv) * 512.f);
  }
  size_t o = ((size_t)blk << 6) + l;
  Bh[o] = hi;
  Bl[o] = lo;
}

// ---------------- vb[t] = sum_k b[k]*W[k][t] ----------------
__global__ __launch_bounds__(256) void wcol_kernel(
    const float* __restrict__ W, const float* __restrict__ b,
    float* __restrict__ vb, int Kd, int N) {
  int t = blockIdx.x * 256 + threadIdx.x;
  int kpb = Kd >> 4;
  int k0 = blockIdx.y * kpb;
  float s = 0.f;
  for (int k = k0; k < k0 + kpb; ++k) s = fmaf(b[k], W[(size_t)k * N + t], s);
  atomicAdd(&vb[t], s);
}

// ---------------- split-f16 MFMA GEMM: C = A@W + vb ----------------
// 64x64 tile, 256 thr / 4 waves; wave w owns rows w*16..+16.
// out_mode: 0 = xi-layout f32; 3 = row-major f32;
//           4 = K split-f16 pack (o16a=hi,o16b=lo*512); 5 = V f16 pack
__global__ __launch_bounds__(256) void gemm_mfma_kernel(
    const f16x8* __restrict__ Ah, const f16x8* __restrict__ Al,
    const f16x8* __restrict__ Bh, const f16x8* __restrict__ Bl,
    const float* __restrict__ vb, float* __restrict__ outf,
    f16x8* __restrict__ o16a, f16x8* __restrict__ o16b, int M, int N, int nk,
    int out_mode) {
  __shared__ __align__(16) float Ts[64][68];
  const int tid = threadIdx.x;
  const int w = tid >> 6, l = tid & 63;
  const int ql = l & 15, g = l >> 4;
  const int bn = blockIdx.x, bm = blockIdx.y;
  const size_t astr = ((size_t)(M >> 4)) << 6;
  const size_t bstr = ((size_t)(N >> 4)) << 6;
  const f16x8* aph = Ah + (((size_t)(bm * 4 + w)) << 6) + l;
  const f16x8* apl = Al + (((size_t)(bm * 4 + w)) << 6) + l;
  const f16x8* bph = Bh + (((size_t)(bn * 4)) << 6) + l;
  const f16x8* bpl = Bl + (((size_t)(bn * 4)) << 6) + l;

  f32x4 cm[4], cx[4];
#pragma unroll
  for (int nf = 0; nf < 4; ++nf) {
    cm[nf] = (f32x4){0.f, 0.f, 0.f, 0.f};
    cx[nf] = (f32x4){0.f, 0.f, 0.f, 0.f};
  }

  f16x8 a0h = aph[0], a0l = apl[0];
  f16x8 b0h[4], b0l[4];
#pragma unroll
  for (int nf = 0; nf < 4; ++nf) {
    b0h[nf] = bph[nf << 6];
    b0l[nf] = bpl[nf << 6];
  }

  for (int kc = 0; kc < nk - 1; ++kc) {
    const size_t ao = (size_t)(kc + 1) * astr;
    const size_t bo = (size_t)(kc + 1) * bstr;
    f16x8 a1h = aph[ao], a1l = apl[ao];
    f16x8 b1h[4], b1l[4];
#pragma unroll
    for (int nf = 0; nf < 4; ++nf) {
      b1h[nf] = bph[bo + (nf << 6)];
      b1l[nf] = bpl[bo + (nf << 6)];
    }
#pragma unroll
    for (int nf = 0; nf < 4; ++nf) {
      cm[nf] = __builtin_amdgcn_mfma_f32_16x16x32_f16(a0h, b0h[nf], cm[nf], 0, 0, 0);
      cx[nf] = __builtin_amdgcn_mfma_f32_16x16x32_f16(a0h, b0l[nf], cx[nf], 0, 0, 0);
      cx[nf] = __builtin_amdgcn_mfma_f32_16x16x32_f16(a0l, b0h[nf], cx[nf], 0, 0, 0);
    }
    a0h = a1h;
    a0l = a1l;
#pragma unroll
    for (int nf = 0; nf < 4; ++nf) {
      b0h[nf] = b1h[nf];
      b0l[nf] = b1l[nf];
    }
  }
#pragma unroll
  for (int nf = 0; nf < 4; ++nf) {
    cm[nf] = __builtin_amdgcn_mfma_f32_16x16x32_f16(a0h, b0h[nf], cm[nf], 0, 0, 0);
    cx[nf] = __builtin_amdgcn_mfma_f32_16x16x32_f16(a0h, b0l[nf], cx[nf], 0, 0, 0);
    cx[nf] = __builtin_amdgcn_mfma_f32_16x16x32_f16(a0l, b0h[nf], cx[nf], 0, 0, 0);
  }

  float vbc[4] = {0.f, 0.f, 0.f, 0.f};
  if (vb) {
#pragma unroll
    for (int nf = 0; nf < 4; ++nf) vbc[nf] = vb[bn * 64 + nf * 16 + ql];
  }

  if (out_mode == 0) {
#pragma unroll
    for (int nf = 0; nf < 4; ++nf)
#pragma unroll
      for (int r = 0; r < 4; ++r) {
        float val = fmaf(cx[nf][r], 0.001953125f, cm[nf][r]) + vbc[nf];
        int m = bm * 64 + w * 16 + (g << 2) + r;
        int n = bn * 64 + nf * 16 + ql;
        int b = m >> 9, s = m & 511, hh = n >> 6, d = n & 63;
        outf[((((size_t)b * 4 + hh) * 512 + s) << 6) + d] = val;
      }
  } else if (out_mode == 3) {
#pragma unroll
    for (int nf = 0; nf < 4; ++nf)
#pragma unroll
      for (int r = 0; r < 4; ++r) {
        float val = fmaf(cx[nf][r], 0.001953125f, cm[nf][r]) + vbc[nf];
        int m = bm * 64 + w * 16 + (g << 2) + r;
        int n = bn * 64 + nf * 16 + ql;
        outf[(size_t)m * N + n] = val;
      }
  } else {
#pragma unroll
    for (int nf = 0; nf < 4; ++nf)
#pragma unroll
      for (int r = 0; r < 4; ++r)
        Ts[w * 16 + (g << 2) + r][nf * 16 + ql] =
            fmaf(cx[nf][r], 0.001953125f, cm[nf][r]) + vbc[nf];
    __syncthreads();
    if (out_mode == 4) {
#pragma unroll
      for (int i = 0; i < 2; ++i) {
        int slot = tid + (i << 8);
        int blk = slot >> 6, l2 = slot & 63;
        int ktl = blk >> 1, dc = blk & 1;
        int key = (ktl << 4) + (l2 & 15);
        int db = (dc << 5) + ((l2 >> 4) << 3);
        f16x8 hi, lo;
#pragma unroll
        for (int j = 0; j < 8; ++j) {
          float v = Ts[key][db + j];
          f16 hv = (f16)v;
          hi[j] = hv;
          lo[j] = (f16)((v - (float)hv) * 512.f);
        }
        size_t o = (((size_t)(bn * 512 + bm * 4 + ktl) * 2 + dc) << 6) + l2;
        o16a[o] = hi;
        o16b[o] = lo;
      }
    } else {
#pragma unroll
      for (int i = 0; i < 2; ++i) {
        int slot = tid + (i << 8);
        int blk = slot >> 6, l2 = slot & 63;
        int dt = blk >> 1, kcl = blk & 1;
        int keyb = (kcl << 5) + ((l2 >> 4) << 3);
        int d = (dt << 4) + (l2 & 15);
        f16x8 v8;
#pragma unroll
        for (int j = 0; j < 8; ++j) v8[j] = (f16)Ts[keyb + j][d];
        size_t o = (((size_t)(bn * 4 + dt) * 256 + bm * 2 + kcl) << 6) + l2;
        o16a[o] = v8;
      }
    }
  }
}

// ---------------- S1: precise scores -> u16 y to global ----------------
__global__ __launch_bounds__(512) void hop_score_kernel(
    const float* __restrict__ xi_in, const f16x8* __restrict__ Khi,
    const f16x8* __restrict__ Klo, const float* __restrict__ log_beta,
    unsigned short* __restrict__ Y) {
  __shared__ float xiq[16][64];
  __shared__ float mxb[8][16];
  __shared__ float mxs[16];
  const int tid = threadIdx.x;
  const int w = tid >> 6, l = tid & 63;
  const int ql = l & 15, g = l >> 4;
  const int bh = blockIdx.x & 7, qtile = blockIdx.x >> 3;
  const int h = bh & 3;
  const size_t base_io = ((size_t)bh * 512 + qtile * 16) * 64;

  float beta = expf(log_beta[h]);
  for (int i = tid; i < 1024; i += 512)
    xiq[i >> 6][i & 63] = xi_in[base_io + i] * beta;
  __syncthreads();

  f16x8 xh0, xh1, xl0, xl1;
#pragma unroll
  for (int j = 0; j < 8; ++j) {
    float x0 = xiq[ql][(g << 3) + j];
    float x1 = xiq[ql][32 + (g << 3) + j];
    f16 h0 = (f16)x0, h1 = (f16)x1;
    xh0[j] = h0; xl0[j] = (f16)((x0 - (float)h0) * 512.f);
    xh1[j] = h1; xl1[j] = (f16)((x1 - (float)h1) * 512.f);
  }

  const f16x8* kb = Khi + (size_t)h * 65536 + l;
  const f16x8* kl = Klo + (size_t)h * 65536 + l;
  const int kt0 = w * 64;

  float mymax = -3.4e38f;
  for (int kt = kt0; kt < kt0 + 64; ++kt) {
    f32x4 c = {0.f, 0.f, 0.f, 0.f};
    c = __builtin_amdgcn_mfma_f32_16x16x32_f16(kb[(size_t)kt * 128], xh0, c, 0, 0, 0);
    c = __builtin_amdgcn_mfma_f32_16x16x32_f16(kb[(size_t)kt * 128 + 64], xh1, c, 0, 0, 0);
    mymax = fmaxf(fmaxf(fmaxf(c[0], c[1]), fmaxf(c[2], c[3])), mymax);
  }
  mymax = fmaxf(mymax, __shfl_xor(mymax, 16, 64));
  mymax = fmaxf(mymax, __shfl_xor(mymax, 32, 64));
  if (l < 16) mxb[w][ql] = mymax;
  __syncthreads();
  if (tid < 16) {
    float m = mxb[0][tid];
#pragma unroll
    for (int ww = 1; ww < 8; ++ww) m = fmaxf(m, mxb[ww][tid]);
    mxs[tid] = m;
  }
  __syncthreads();
  const float mh = mxs[ql] * 0.5f;

  const size_t Ybase = (size_t)(bh * 32 + qtile) * 131072;
  for (int kt = kt0; kt < kt0 + 64; ++kt) {
    f16x8 a0 = kb[(size_t)kt * 128], a1 = kb[(size_t)kt * 128 + 64];
    f16x8 b0 = kl[(size_t)kt * 128], b1 = kl[(size_t)kt * 128 + 64];
    f32x4 cm = {0.f, 0.f, 0.f, 0.f}, cx = {0.f, 0.f, 0.f, 0.f};
    cm = __builtin_amdgcn_mfma_f32_16x16x32_f16(a0, xh0, cm, 0, 0, 0);
    cm = __builtin_amdgcn_mfma_f32_16x16x32_f16(a1, xh1, cm, 0, 0, 0);
    cx = __builtin_amdgcn_mfma_f32_16x16x32_f16(b0, xh0, cx, 0, 0, 0);
    cx = __builtin_amdgcn_mfma_f32_16x16x32_f16(a0, xl0, cx, 0, 0, 0);
    cx = __builtin_amdgcn_mfma_f32_16x16x32_f16(b1, xh1, cx, 0, 0, 0);
    cx = __builtin_amdgcn_mfma_f32_16x16x32_f16(a1, xl1, cx, 0, 0, 0);
    ushort4 uv;
    unsigned short* up = (unsigned short*)&uv;
#pragma unroll
    for (int r = 0; r < 4; ++r) {
      float s = fmaf(cx[r], 0.001953125f, cm[r]);
      float y = fmaf(s, 0.5f, -mh);
      float uq = fmaf(y, QSCALE, QOFF * QSCALE + 0.5f);
      uq = fminf(fmaxf(uq, 0.f), 65535.f);
      up[r] = (unsigned short)(int)uq;
    }
    *(ushort4*)&Y[Ybase + (size_t)(kt >> 1) * 512 + ql * 32 + (kt & 1) * 16 +
                  (g << 2)] = uv;
  }
}

// ---------------- S2: exact entmax tau per row ----------------
__global__ __launch_bounds__(256) void hop_tau_kernel(
    const unsigned short* __restrict__ Y, float* __restrict__ tau) {
  const int row = blockIdx.x;
  const int bh = row >> 9, qi = row & 511;
  const int qtile = qi >> 4, ql = qi & 15;
  const size_t yb = (size_t)(bh * 32 + qtile) * 131072 + ql * 32;
  const int t = threadIdx.x;
  const uint4* p = (const uint4*)(Y + yb + (size_t)t * 512);
  float y[32];
#pragma unroll
  for (int v = 0; v < 4; ++v) {
    uint4 u = p[v];
    unsigned a[4] = {u.x, u.y, u.z, u.w};
#pragma unroll
    for (int e = 0; e < 4; ++e) {
      y[v * 8 + e * 2] = fmaf((float)(a[e] & 0xffffu), QINV, -QOFF);
      y[v * 8 + e * 2 + 1] = fmaf((float)(a[e] >> 16), QINV, -QOFF);
    }
  }
  __shared__ float rb[4];
  __shared__ float rb3[4][3];
  float lo = -1.1f, hi = 0.1f;
  const int wi = t >> 6, lane = t & 63;
#pragma unroll 1
  for (int it = 0; it < 16; ++it) {
    float tv = 0.5f * (lo + hi);
    float f = 0.f;
#pragma unroll
    for (int i = 0; i < 32; ++i) {
      float d = fmaxf(y[i] - tv, 0.f);
      f = fmaf(d, d, f);
    }
    f = wred_add(f);
    if (lane == 0) rb[wi] = f;
    __syncthreads();
    float tot = rb[0] + rb[1] + rb[2] + rb[3];
    if (tot >= 1.f) lo = tv; else hi = tv;
    __syncthreads();
  }
  float kk = 0.f, s1 = 0.f, s2 = 0.f;
#pragma unroll
  for (int i = 0; i < 32; ++i) {
    if (y[i] > lo) { kk += 1.f; s1 += y[i]; s2 = fmaf(y[i], y[i], s2); }
  }
  kk = wred_add(kk);
  s1 = wred_add(s1);
  s2 = wred_add(s2);
  if (lane == 0) { rb3[wi][0] = kk; rb3[wi][1] = s1; rb3[wi][2] = s2; }
  __syncthreads();
  if (t == 0) {
    float K = 0.f, S1 = 0.f, S2 = 0.f;
#pragma unroll
    for (int ww = 0; ww < 4; ++ww) {
      K += rb3[ww][0]; S1 += rb3[ww][1]; S2 += rb3[ww][2];
    }
    float mean = S1 / K;
    float ss = fmaf(-mean, S1, S2);
    float delta = (1.f - ss) / K;
    tau[row] = delta > 0.f ? mean - sqrtf(delta) : mean;
  }
}

// ---------------- S3: weights + PV MFMA ----------------
__global__ __launch_bounds__(512) void hop_pv_kernel(
    const unsigned short* __restrict__ Y, const f16x8* __restrict__ Vp,
    const float* __restrict__ tau, float* __restrict__ xi_out) {
  __shared__ float outp[8][16][64];
  __shared__ float taus[16];
  const int tid = threadIdx.x;
  const int w = tid >> 6, l = tid & 63;
  const int ql = l & 15, g = l >> 4;
  const int bh = blockIdx.x & 7, qtile = blockIdx.x >> 3;
  const int h = bh & 3;
  const size_t base_io = ((size_t)bh * 512 + qtile * 16) * 64;

  if (tid < 16) taus[tid] = tau[bh * 512 + qtile * 16 + tid];
  __syncthreads();
  const float t1 = taus[ql];
  const size_t Ybase = (size_t)(bh * 32 + qtile) * 131072;
  const f16x8* vb = Vp + (size_t)h * 65536 + l;

  f32x4 m2[4];
#pragma unroll
  for (int dt = 0; dt < 4; ++dt) m2[dt] = (f32x4){0.f, 0.f, 0.f, 0.f};

  for (int kc = 0; kc < 32; ++kc) {
    const int chunk = w * 32 + kc;
    uint4 uv = *(const uint4*)(Y + Ybase + (size_t)chunk * 512 + ql * 32 +
                               (g << 3));
    unsigned a[4] = {uv.x, uv.y, uv.z, uv.w};
    f16x8 a2;
#pragma unroll
    for (int e = 0; e < 4; ++e) {
      float y0 = fmaf((float)(a[e] & 0xffffu), QINV, -QOFF);
      float y1 = fmaf((float)(a[e] >> 16), QINV, -QOFF);
      float p0 = fmaxf(y0 - t1, 0.f);
      float p1 = fmaxf(y1 - t1, 0.f);
      a2[e * 2] = (f16)(p0 * p0);
      a2[e * 2 + 1] = (f16)(p1 * p1);
    }
#pragma unroll
    for (int dt = 0; dt < 4; ++dt) {
      f16x8 vf = vb[(((size_t)dt * 256 + chunk) << 6)];
      m2[dt] = __builtin_amdgcn_mfma_f32_16x16x32_f16(a2, vf, m2[dt], 0, 0, 0);
    }
  }
#pragma unroll
  for (int dt = 0; dt < 4; ++dt)
#pragma unroll
    for (int r = 0; r < 4; ++r)
      outp[w][(g << 2) + r][dt * 16 + ql] = m2[dt][r];
  __syncthreads();
  for (int i = tid; i < 1024; i += 512) {
    float s = 0.f;
#pragma unroll
    for (int ww = 0; ww < 8; ++ww) s += outp[ww][i >> 6][i & 63];
    xi_out[base_io + i] = s;
  }
}

// ---------------- converged copy ----------------
__global__ __launch_bounds__(256) void conv_copy_kernel(
    const float* __restrict__ xi, float* __restrict__ out) {
  int o4 = blockIdx.x * 256 + threadIdx.x;
  int o = o4 << 2;
  int dd = o & 63, hq = (o >> 6) & 3, sq = (o >> 8) & 511, bq = o >> 17;
  float4 v =
      *(const float4*)&xi[((((size_t)bq << 2) + hq) * 512 + sq) * 64 + dd];
  *(float4*)&out[o] = v;
}

extern "C" void kernel_launch(void* const* d_in, const int* in_sizes, int n_in,
                              void* d_out, int out_size, void* d_ws,
                              size_t ws_size, hipStream_t stream) {
  (void)in_sizes; (void)n_in; (void)out_size; (void)ws_size;
  const float* hidden = (const float*)d_in[0];
  const float* memory = (const float*)d_in[1];
  const float* Wq = (const float*)d_in[2];
  const float* Wk = (const float*)d_in[3];
  const float* Wv = (const float*)d_in[4];
  const float* Wo = (const float*)d_in[5];
  const float* log_beta = (const float*)d_in[6];
  const float* g_s = (const float*)d_in[7];
  const float* b_s = (const float*)d_in[8];
  const float* g_m = (const float*)d_in[9];
  const float* b_m = (const float*)d_in[10];
  float* out = (float*)d_out;

  float* ws = (float*)d_ws;
  float* mu_h = ws;                 // 1024
  float* rs_h = ws + 1024;          // 1024
  float* mu_m = ws + 2048;          // 8192
  float* rs_m = ws + 10240;         // 8192
  float* xiA = ws + 18432;          // 262144
  float* xiB = ws + 280576;         // 262144
  float* vb_q = ws + 542720;        // 256
  float* vb_k = ws + 542976;        // 256
  float* vb_v = ws + 543232;        // 256
  float* tau = ws + 543488;         // 4096
  f16x8* Khi = (f16x8*)(ws + 548864);  // 262144 f16x8 = 4MB
  f16x8* Klo = Khi + 262144;
  f16x8* Vp = Klo + 262144;
  f16x8* Bqh = Vp + 262144;         // 65536
  f16x8* Bql = Bqh + 65536;
  f16x8* Bkh = Bql + 65536;         // 32768
  f16x8* Bkl = Bkh + 32768;
  f16x8* Bvh = Bkl + 32768;
  f16x8* Bvl = Bvh + 32768;
  f16x8* Boh = Bvl + 32768;         // 65536
  f16x8* Bol = Boh + 65536;
  // Y (64MB) aliases the A-frag packs (stream-ordered: packs consumed
  // by the GEMMs before the first hop_score writes Y; Ax written after
  // the last hop_pv reads Y). All recomputed every call.
  unsigned short* Y = (unsigned short*)(Bol + 65536);
  f16x8* Amh = (f16x8*)Y;           // 1048576 (16MB)
  f16x8* Aml = Amh + 1048576;       // 16MB
  f16x8* Ahh = Aml + 1048576;       // 262144 (4MB)
  f16x8* Ahl = Ahh + 262144;        // 4MB
  f16x8* Axh = Ahl + 262144;        // 32768 (0.5MB)
  f16x8* Axl = Axh + 32768;         // 0.5MB

  ln_stats_kernel<<<1024, 256, 0, stream>>>(hidden, 2048, mu_h, rs_h);
  ln_stats_kernel<<<8192, 256, 0, stream>>>(memory, 1024, mu_m, rs_m);
  hipMemsetAsync(vb_q, 0, 3 * 256 * sizeof(float), stream);

  split_a_kernel<<<1024, 256, 0, stream>>>(hidden, mu_h, rs_h, Ahh, Ahl, 1024,
                                           2048, 0);
  split_a_kernel<<<4096, 256, 0, stream>>>(memory, mu_m, rs_m, Amh, Aml, 8192,
                                           1024, 0);
  split_w_kernel<<<256, 256, 0, stream>>>(Wq, g_s, Bqh, Bql, 2048, 256);
  split_w_kernel<<<128, 256, 0, stream>>>(Wk, g_m, Bkh, Bkl, 1024, 256);
  split_w_kernel<<<128, 256, 0, stream>>>(Wv, g_m, Bvh, Bvl, 1024, 256);
  split_w_kernel<<<256, 256, 0, stream>>>(Wo, nullptr, Boh, Bol, 256, 2048);
  wcol_kernel<<<dim3(1, 16), 256, 0, stream>>>(Wq, b_s, vb_q, 2048, 256);
  wcol_kernel<<<dim3(1, 16), 256, 0, stream>>>(Wk, b_m, vb_k, 1024, 256);
  wcol_kernel<<<dim3(1, 16), 256, 0, stream>>>(Wv, b_m, vb_v, 1024, 256);

  // Q -> xiA (xi layout)
  gemm_mfma_kernel<<<dim3(4, 16), 256, 0, stream>>>(
      Ahh, Ahl, Bqh, Bql, vb_q, xiA, nullptr, nullptr, 1024, 256, 64, 0);
  // K -> Khi/Klo
  gemm_mfma_kernel<<<dim3(4, 128), 256, 0, stream>>>(
      Amh, Aml, Bkh, Bkl, vb_k, nullptr, Khi, Klo, 8192, 256, 32, 4);
  // V -> Vp
  gemm_mfma_kernel<<<dim3(4, 128), 256, 0, stream>>>(
      Amh, Aml, Bvh, Bvl, vb_v, nullptr, Vp, nullptr, 8192, 256, 32, 5);

  float* xin = xiA;
  float* xout = xiB;
  for (int step = 0; step < 3; ++step) {
    hop_score_kernel<<<256, 512, 0, stream>>>(xin, Khi, Klo, log_beta, Y);
    hop_tau_kernel<<<4096, 256, 0, stream>>>(Y, tau);
    hop_pv_kernel<<<256, 512, 0, stream>>>(Y, Vp, tau, xout);
    float* t = xin; xin = xout; xout = t;
  }

  // output = converged @ Wo
  split_a_kernel<<<128, 256, 0, stream>>>(xin, nullptr, nullptr, Axh, Axl,
                                          1024, 256, 1);
  gemm_mfma_kernel<<<dim3(32, 16), 256, 0, stream>>>(
      Axh, Axl, Boh, Bol, nullptr, out, nullptr, nullptr, 1024, 2048, 8, 3);
  conv_copy_kernel<<<256, 256, 0, stream>>>(xin, out + 2097152);
}